// Round 3
// baseline (780.311 us; speedup 1.0000x reference)
//
#include <hip/hip_runtime.h>
#include <hip/hip_bf16.h>

typedef __bf16 bf16_t;
typedef __bf16 bf16x8 __attribute__((ext_vector_type(8)));
typedef __bf16 bf16x4 __attribute__((ext_vector_type(4)));
typedef __bf16 bf16x2 __attribute__((ext_vector_type(2)));
typedef float f32x4 __attribute__((ext_vector_type(4)));

#define MFMA16(a,b,c) __builtin_amdgcn_mfma_f32_16x16x32_bf16((a),(b),(c),0,0,0)
#define AS3(p) ((__attribute__((address_space(3))) void*)(p))
#define AS1(p) ((const __attribute__((address_space(1))) void*)(p))

constexpr int B_ = 4, L_ = 2048, E_ = 2048, H_ = 16, HD_ = 128;
constexpr size_t QK_ELEMS = (size_t)B_ * H_ * L_ * HD_;    // 16,777,216
constexpr size_t NX = (size_t)B_ * L_ * E_;                // 16,777,216
constexpr size_t NW = (size_t)3 * E_ * E_;                 // 12,582,912

// ---------------------------------------------------------------------------
// Kernel 0: fp32 -> bf16 conversion of X and W into one contiguous dst
// (dst lives in d_out's first 58.7MB; overwritten later by attn's output).
// ---------------------------------------------------------------------------
__global__ __launch_bounds__(256) void cvt(
    const float* __restrict__ X, const float* __restrict__ W, bf16_t* __restrict__ dst)
{
  size_t e = ((size_t)blockIdx.x * 256 + threadIdx.x) * 4;
  f32x4 v = (e < NX) ? *(const f32x4*)&X[e] : *(const f32x4*)&W[e - NX];
  bf16x4 o;
  for (int u = 0; u < 4; ++u) o[u] = (__bf16)v[u];
  *(bf16x4*)&dst[e] = o;
}

// ---------------------------------------------------------------------------
// Kernel 1: y = Xb @ Wb^T + b, fused with F.normalize for q/k.
// 128x128 tile, BK=32, 4 waves 2x2.
//   - LDS granule-transposed layout: per 16-row subtile, granule (q,r)
//     (16B = 8 bf16 of row sub*16+r, k-cols q*8..q*8+7) lives at byte
//     (q*16+r)*16. MFMA fragment read = subtile_base + lane*16B ->
//     2 lanes/bank, conflict-free. Realized by PRE-PERMUTING the per-lane
//     global source (lane j loads row j&15, chunk j>>4) while
//     global_load_lds writes linearly (both-sides-or-neither, rule #21).
//   - 2-phase double-buffer: issue next K-tile's global_load_lds BEFORE
//     compute; ONE barrier per K-step (barrier's vmcnt(0) drain completes
//     the prefetch).
//   - Epilogue fuses L2 normalization for q/k: the 128-col n-tile is one
//     full head (3*HD=384, n0%384 in {0,128,256}), so sum-of-squares
//     reduces in-block (shfl over 16-lane group + 1KB LDS exchange across
//     the two wn waves). Normalizes pre-rounding fp32 values.
// Epilogue scatters q,k -> [B,H,L,HD] and v -> vT [B,H,HD,L] (bf16).
// ---------------------------------------------------------------------------
__global__ __launch_bounds__(256) void gemm_qkv(
    const bf16_t* __restrict__ Xb, const bf16_t* __restrict__ Wb, const float* __restrict__ bias,
    bf16_t* __restrict__ q, bf16_t* __restrict__ k, bf16_t* __restrict__ vT)
{
  __shared__ alignas(16) bf16_t As[2][128 * 32];   // dbuf, granule-transposed
  __shared__ alignas(16) bf16_t Bs[2][128 * 32];
  const int tid = threadIdx.x;
  const int wave = tid >> 6, lane = tid & 63;
  const int wm = wave >> 1, wn = wave & 1;
  const int m0 = blockIdx.y * 128, n0 = blockIdx.x * 128;

  // staging source (pre-permuted): lane j covers (row = j&15, kchunk = j>>4)
  // of its wave's 16-row subtile; global_load_lds dest = base + j*16B.
  const int sr = lane & 15, sq8 = (lane >> 4) * 8;
  const bf16_t* gA = &Xb[(size_t)(m0 + wave * 32 + sr) * E_ + sq8];
  const bf16_t* gB = &Wb[(size_t)(n0 + wave * 32 + sr) * E_ + sq8];
  bf16_t* lA = &As[0][wave * 1024];   // wave owns subtiles 2w, 2w+1 (512 elems each)
  bf16_t* lB = &Bs[0][wave * 1024];

#define STAGE(c, k0) do { \
    __builtin_amdgcn_global_load_lds(AS1(gA + (k0)),           AS3(lA + (c) * 4096),       16, 0, 0); \
    __builtin_amdgcn_global_load_lds(AS1(gA + 16 * E_ + (k0)), AS3(lA + (c) * 4096 + 512), 16, 0, 0); \
    __builtin_amdgcn_global_load_lds(AS1(gB + (k0)),           AS3(lB + (c) * 4096),       16, 0, 0); \
    __builtin_amdgcn_global_load_lds(AS1(gB + 16 * E_ + (k0)), AS3(lB + (c) * 4096 + 512), 16, 0, 0); \
  } while (0)

  const f32x4 fzero = {0.f, 0.f, 0.f, 0.f};
  f32x4 acc[4][4];
  for (int i = 0; i < 4; ++i)
    for (int j = 0; j < 4; ++j) acc[i][j] = fzero;

  STAGE(0, 0);
  __syncthreads();            // vmcnt(0) drain: buf0 ready
  int cur = 0;
  for (int t = 0; t < 64; ++t) {
    if (t < 63) STAGE(cur ^ 1, (t + 1) * 32);   // issue-early: flight overlaps compute
    bf16x8 af[4], bfr[4];
    for (int mt = 0; mt < 4; ++mt) af[mt]  = *(const bf16x8*)&As[cur][(wm * 4 + mt) * 512 + lane * 8];
    for (int nt = 0; nt < 4; ++nt) bfr[nt] = *(const bf16x8*)&Bs[cur][(wn * 4 + nt) * 512 + lane * 8];
    __builtin_amdgcn_s_setprio(1);
    for (int mt = 0; mt < 4; ++mt)
      for (int nt = 0; nt < 4; ++nt)
        acc[mt][nt] = MFMA16(af[mt], bfr[nt], acc[mt][nt]);
    __builtin_amdgcn_s_setprio(0);
    __syncthreads();          // all reads of cur done; prefetch into cur^1 complete
    cur ^= 1;
  }
#undef STAGE

  const int b  = m0 >> 11;            // m0 / 2048
  const int l0 = m0 & (L_ - 1);
  const int h  = n0 / 384;
  const int which = (n0 % 384) >> 7;  // 0=q 1=k 2=v
  const int rlane = (lane >> 4) << 2; // C/D row base = (lane>>4)*4
  const int clane = lane & 15;        // C/D col = lane&15

  float bcol[4];
  for (int nt = 0; nt < 4; ++nt)
    bcol[nt] = bias[n0 + wn * 64 + nt * 16 + clane];

  if (which < 2) {
    // fused L2 normalize over this head's 128 columns (all inside this block)
    float* NormS = (float*)&As[0][0];   // [128 rows][2 wn-halves] fp32, 1KB, aliases As
    for (int mt = 0; mt < 4; ++mt)
      for (int r = 0; r < 4; ++r) {
        float sq = 0.f;
        for (int nt = 0; nt < 4; ++nt) {
          float v = acc[mt][nt][r] + bcol[nt];
          acc[mt][nt][r] = v;           // keep biased value for the write
          sq += v * v;
        }
        for (int off = 8; off; off >>= 1) sq += __shfl_xor(sq, off);  // 16-lane row group
        if (clane == 0) NormS[(wm * 64 + mt * 16 + rlane + r) * 2 + wn] = sq;
      }
    __syncthreads();
    float invn[4][4];
    for (int mt = 0; mt < 4; ++mt)
      for (int r = 0; r < 4; ++r) {
        int ll = wm * 64 + mt * 16 + rlane + r;
        float tot = NormS[ll * 2] + NormS[ll * 2 + 1];
        invn[mt][r] = 1.0f / fmaxf(sqrtf(tot), 1e-12f);   // matches F.normalize eps
      }
    bf16_t* base = ((which == 0) ? q : k) + ((size_t)(b * H_ + h) * L_) * HD_;
    for (int mt = 0; mt < 4; ++mt)
      for (int r = 0; r < 4; ++r) {
        int l = l0 + wm * 64 + mt * 16 + rlane + r;
        bf16_t* rowp = base + (size_t)l * HD_;
        for (int nt = 0; nt < 4; ++nt) {
          int hd = wn * 64 + nt * 16 + clane;
          rowp[hd] = (__bf16)(acc[mt][nt][r] * invn[mt][r]);
        }
      }
  } else {
    bf16_t* base = vT + ((size_t)(b * H_ + h) * HD_) * L_;
    for (int mt = 0; mt < 4; ++mt)
      for (int r = 0; r < 4; ++r) {
        int l = l0 + wm * 64 + mt * 16 + rlane + r;
        for (int nt = 0; nt < 4; ++nt) {
          int hd = wn * 64 + nt * 16 + clane;
          base[(size_t)hd * L_ + l] = (__bf16)(acc[mt][nt][r] + bcol[nt]);
        }
      }
  }
}

// ---------------------------------------------------------------------------
// Kernel 3: flash-style attention (verified in round 1; unchanged).
//   - cosine scores (|S|<=1) => softmax-lite: p=exp(s), denom reduced once.
//   - Q fragments in registers; private P buffer; 2 barriers/iter.
//   - T14 async staging; T5 setprio.
// LDS: Ks 16KB + Vts 16KB + Ps 16KB = 48KB. Output fp32 [B,L,H,HD].
// ---------------------------------------------------------------------------
__device__ __forceinline__ int swz128(int r, int c) {
  return r * 128 + ((((c >> 3) ^ (r & 15)) & 15) << 3) + (c & 7);
}
__device__ __forceinline__ int swz64(int r, int c) {
  return r * 64 + ((((c >> 3) ^ (r & 7)) & 7) << 3) + (c & 7);
}

__global__ __launch_bounds__(256) void attn(
    const bf16_t* __restrict__ q, const bf16_t* __restrict__ k,
    const bf16_t* __restrict__ vT, float* __restrict__ out)
{
  __shared__ alignas(16) bf16_t Ks[64 * 128];   // [j][d], swizzled
  __shared__ alignas(16) bf16_t Vts[128 * 64];  // [d][j], swizzled
  __shared__ alignas(16) bf16_t Ps[128 * 64];   // [l][j], swizzled (own-wave rows)

  const int tid = threadIdx.x, wave = tid >> 6, lane = tid & 63;
  const int bh = blockIdx.y;
  const int q0 = blockIdx.x * 128;
  const int rowf = lane & 15, kq8 = (lane >> 4) * 8;

  const bf16_t* qbase = q + ((size_t)bh * L_ + q0) * HD_;
  const bf16_t* kbh = k + (size_t)bh * L_ * HD_;
  const bf16_t* vbh = vT + (size_t)bh * HD_ * L_;

  // Q fragments: loop-invariant, straight from global (one-time, L2-served)
  bf16x8 qf[4][2];
  for (int kk4 = 0; kk4 < 4; ++kk4)
    for (int mt = 0; mt < 2; ++mt)
      qf[kk4][mt] = *(const bf16x8*)&qbase[(size_t)(wave * 32 + mt * 16 + rowf) * HD_ + kk4 * 32 + kq8];

  const f32x4 fzero = {0.f, 0.f, 0.f, 0.f};
  f32x4 o[2][8];
  for (int mt = 0; mt < 2; ++mt)
    for (int nt = 0; nt < 8; ++nt) o[mt][nt] = fzero;
  float lrow[2][4];
  for (int mt = 0; mt < 2; ++mt)
    for (int r = 0; r < 4; ++r) lrow[mt][r] = 0.f;

  // staging registers (async prefetch)
  bf16x8 kreg[4], vreg[4];

  // ---- prologue: tile 0 load + store ----
  for (int i = 0; i < 4; ++i) {
    int e = (i * 256 + tid) * 8;
    kreg[i] = *(const bf16x8*)&kbh[e];
  }
  for (int i = 0; i < 4; ++i) {
    int e = (i * 256 + tid) * 8;
    int d = e >> 6, c = e & 63;
    vreg[i] = *(const bf16x8*)&vbh[(size_t)d * L_ + c];
  }
  for (int i = 0; i < 4; ++i) {
    int e = (i * 256 + tid) * 8;
    *(bf16x8*)&Ks[swz128(e >> 7, e & 127)] = kreg[i];
  }
  for (int i = 0; i < 4; ++i) {
    int e = (i * 256 + tid) * 8;
    int d = e >> 6, c = e & 63;
    *(bf16x8*)&Vts[swz64(d, c)] = vreg[i];
  }
  __syncthreads();

  for (int j0 = 0; j0 < L_; j0 += 64) {
    const bool more = (j0 + 64 < L_);
    // issue next tile's loads now; latency hides under QK^T + softmax + PV
    if (more) {
      const int jn = j0 + 64;
      for (int i = 0; i < 4; ++i) {
        int e = (i * 256 + tid) * 8;
        kreg[i] = *(const bf16x8*)&kbh[(size_t)jn * HD_ + e];
      }
      for (int i = 0; i < 4; ++i) {
        int e = (i * 256 + tid) * 8;
        int d = e >> 6, c = e & 63;
        vreg[i] = *(const bf16x8*)&vbh[(size_t)d * L_ + jn + c];
      }
    }

    // S = Q K^T
    f32x4 s[2][4];
    for (int mt = 0; mt < 2; ++mt)
      for (int nt = 0; nt < 4; ++nt) s[mt][nt] = fzero;
    __builtin_amdgcn_s_setprio(1);
    for (int kk = 0; kk < 128; kk += 32) {
      bf16x8 bk4[4];
      for (int nt = 0; nt < 4; ++nt) bk4[nt] = *(const bf16x8*)&Ks[swz128(nt * 16 + rowf, kk + kq8)];
      for (int mt = 0; mt < 2; ++mt)
        for (int nt = 0; nt < 4; ++nt)
          s[mt][nt] = MFMA16(qf[kk >> 5][mt], bk4[nt], s[mt][nt]);
    }
    __builtin_amdgcn_s_setprio(0);

    // softmax-lite: |s| <= 1, so p = exp(s) is unconditionally stable.
    for (int mt = 0; mt < 2; ++mt)
      for (int nt = 0; nt < 4; ++nt)
        for (int r = 0; r < 4; ++r) {
          float p = __expf(s[mt][nt][r]);
          lrow[mt][r] += p;
          int rr = wave * 32 + mt * 16 + ((lane >> 4) << 2) + r;
          int cc = nt * 16 + (lane & 15);
          Ps[swz64(rr, cc)] = (__bf16)p;
        }

    // O += P @ V   (P rows are own-wave only: intra-wave lgkmcnt ordering)
    __builtin_amdgcn_s_setprio(1);
    for (int kk = 0; kk < 64; kk += 32) {
      bf16x8 ap[2];
      for (int mt = 0; mt < 2; ++mt)
        ap[mt] = *(const bf16x8*)&Ps[swz64(wave * 32 + mt * 16 + rowf, kk + kq8)];
      for (int nt = 0; nt < 8; ++nt) {
        bf16x8 bvv = *(const bf16x8*)&Vts[swz64(nt * 16 + rowf, kk + kq8)];
        for (int mt = 0; mt < 2; ++mt)
          o[mt][nt] = MFMA16(ap[mt], bvv, o[mt][nt]);
      }
    }
    __builtin_amdgcn_s_setprio(0);

    __syncthreads();          // all waves done reading Ks/Vts
    if (more) {
      for (int i = 0; i < 4; ++i) {
        int e = (i * 256 + tid) * 8;
        *(bf16x8*)&Ks[swz128(e >> 7, e & 127)] = kreg[i];
      }
      for (int i = 0; i < 4; ++i) {
        int e = (i * 256 + tid) * 8;
        int d = e >> 6, c = e & 63;
        *(bf16x8*)&Vts[swz64(d, c)] = vreg[i];
      }
      __syncthreads();
    }
  }

  // epilogue: single denom reduce, divide, write fp32 out [B][L][H][HD]
  const int b = bh >> 4, h = bh & 15;
  for (int mt = 0; mt < 2; ++mt) {
    for (int r = 0; r < 4; ++r) {
      float lsum = lrow[mt][r];
      for (int off = 8; off; off >>= 1) lsum += __shfl_xor(lsum, off);
      float inv = 1.0f / lsum;
      int l = q0 + wave * 32 + mt * 16 + ((lane >> 4) << 2) + r;
      float* op = out + (((size_t)b * L_ + l) * H_ + h) * HD_;
      for (int nt = 0; nt < 8; ++nt) {
        int d = nt * 16 + (lane & 15);
        op[d] = o[mt][nt][r] * inv;
      }
    }
  }
}

// ---------------------------------------------------------------------------
extern "C" void kernel_launch(void* const* d_in, const int* in_sizes, int n_in,
                              void* d_out, int out_size, void* d_ws, size_t ws_size,
                              hipStream_t stream)
{
  const float* X    = (const float*)d_in[0];   // [4,2048,2048] fp32
  const float* W    = (const float*)d_in[1];   // [6144,2048] fp32
  const float* bias = (const float*)d_in[2];   // [6144] fp32
  float* out = (float*)d_out;                  // [4,2048,2048] fp32

  // bf16 copies of X and W live inside d_out (58.7MB < 67.1MB); d_out is not
  // written by anything until attn, which runs after gemm_qkv has consumed them.
  bf16_t* Xb = (bf16_t*)d_out;
  bf16_t* Wb = Xb + NX;

  bf16_t* q  = (bf16_t*)d_ws;                  // [B,H,L,HD] 32MB (L2-normalized)
  bf16_t* k  = q + QK_ELEMS;                   // 32MB (L2-normalized)
  bf16_t* vT = k + QK_ELEMS;                   // [B,H,HD,L] 32MB

  cvt<<<dim3((NX + NW) / (256 * 4)), 256, 0, stream>>>(X, W, Xb);
  gemm_qkv<<<dim3(48, 64), 256, 0, stream>>>(Xb, Wb, bias, q, k, vT);
  attn<<<dim3(16, 64), 256, 0, stream>>>(q, k, vT, out);
}

// Round 4
// 779.955 us; speedup vs baseline: 1.0005x; 1.0005x over previous
//
#include <hip/hip_runtime.h>
#include <hip/hip_bf16.h>

typedef __bf16 bf16_t;
typedef __bf16 bf16x8 __attribute__((ext_vector_type(8)));
typedef __bf16 bf16x4 __attribute__((ext_vector_type(4)));
typedef __bf16 bf16x2 __attribute__((ext_vector_type(2)));
typedef float f32x4 __attribute__((ext_vector_type(4)));

#define MFMA16(a,b,c) __builtin_amdgcn_mfma_f32_16x16x32_bf16((a),(b),(c),0,0,0)
#define AS3(p) ((__attribute__((address_space(3))) void*)(p))
#define AS1(p) ((const __attribute__((address_space(1))) void*)(p))

constexpr int B_ = 4, L_ = 2048, E_ = 2048, H_ = 16, HD_ = 128;
constexpr size_t QK_ELEMS = (size_t)B_ * H_ * L_ * HD_;    // 16,777,216
constexpr size_t NX = (size_t)B_ * L_ * E_;                // 16,777,216
constexpr size_t NW = (size_t)3 * E_ * E_;                 // 12,582,912

// ---------------------------------------------------------------------------
// Kernel 0: fp32 -> bf16 conversion of X and W into one contiguous dst
// (dst lives in d_out's first 58.7MB; overwritten later by attn's output).
// ---------------------------------------------------------------------------
__global__ __launch_bounds__(256) void cvt(
    const float* __restrict__ X, const float* __restrict__ W, bf16_t* __restrict__ dst)
{
  size_t e = ((size_t)blockIdx.x * 256 + threadIdx.x) * 4;
  f32x4 v = (e < NX) ? *(const f32x4*)&X[e] : *(const f32x4*)&W[e - NX];
  bf16x4 o;
  for (int u = 0; u < 4; ++u) o[u] = (__bf16)v[u];
  *(bf16x4*)&dst[e] = o;
}

// ---------------------------------------------------------------------------
// Kernel 1: y = Xb @ Wb^T + b, fused with F.normalize for q/k.
// 128x128 tile, BK=32, 4 waves 2x2, m97 2-barrier schedule (round-2 proven:
// the single-barrier issue-early dbuf variant REGRESSED 296->432us, r3).
//   - Granule-transposed LDS layout (r3-proven conflict-free): per 16-row
//     subtile, granule (q,r) = 16B of row r, k-chunk q lives at (q*16+r)*16B.
//     Achieved by pre-permuting the per-lane global source (lane j loads
//     row j&15, chunk j>>4) while global_load_lds writes linearly
//     (both-sides-or-neither, rule #21). Fragment read = subtile_base +
//     lane*16B -> sequential, 0 conflicts (r3 PMC).
//   - Epilogue fuses L2 normalization for q/k (r3-proven correct): the
//     128-col n-tile is one full head (3*HD=384), sum-of-squares reduces
//     in-block (shfl over 16-lane group + 1KB LDS exchange across wn waves).
// Epilogue scatters q,k -> [B,H,L,HD] and v -> vT [B,H,HD,L] (bf16).
// ---------------------------------------------------------------------------
__global__ __launch_bounds__(256) void gemm_qkv(
    const bf16_t* __restrict__ Xb, const bf16_t* __restrict__ Wb, const float* __restrict__ bias,
    bf16_t* __restrict__ q, bf16_t* __restrict__ k, bf16_t* __restrict__ vT)
{
  __shared__ alignas(16) bf16_t As[128 * 32];   // granule-transposed, 8KB
  __shared__ alignas(16) bf16_t Bs[128 * 32];   // 8KB
  const int tid = threadIdx.x;
  const int wave = tid >> 6, lane = tid & 63;
  const int wm = wave >> 1, wn = wave & 1;
  const int m0 = blockIdx.y * 128, n0 = blockIdx.x * 128;

  // staging source (pre-permuted): lane j covers (row = j&15, kchunk = j>>4)
  // of its wave's 16-row subtile; global_load_lds dest = base + j*16B.
  const int sr = lane & 15, sq8 = (lane >> 4) * 8;
  const bf16_t* gA = &Xb[(size_t)(m0 + wave * 32 + sr) * E_ + sq8];
  const bf16_t* gB = &Wb[(size_t)(n0 + wave * 32 + sr) * E_ + sq8];
  bf16_t* lA = &As[wave * 1024];   // wave owns subtiles 2w (at +0), 2w+1 (at +512)
  bf16_t* lB = &Bs[wave * 1024];

  const f32x4 fzero = {0.f, 0.f, 0.f, 0.f};
  f32x4 acc[4][4];
  for (int i = 0; i < 4; ++i)
    for (int j = 0; j < 4; ++j) acc[i][j] = fzero;

  for (int k0 = 0; k0 < E_; k0 += 32) {
    __syncthreads();
    __builtin_amdgcn_global_load_lds(AS1(gA + k0),            AS3(lA),       16, 0, 0);
    __builtin_amdgcn_global_load_lds(AS1(gA + 16 * E_ + k0),  AS3(lA + 512), 16, 0, 0);
    __builtin_amdgcn_global_load_lds(AS1(gB + k0),            AS3(lB),       16, 0, 0);
    __builtin_amdgcn_global_load_lds(AS1(gB + 16 * E_ + k0),  AS3(lB + 512), 16, 0, 0);
    __syncthreads();
    bf16x8 af[4], bfr[4];
    for (int mt = 0; mt < 4; ++mt) af[mt]  = *(const bf16x8*)&As[(wm * 4 + mt) * 512 + lane * 8];
    for (int nt = 0; nt < 4; ++nt) bfr[nt] = *(const bf16x8*)&Bs[(wn * 4 + nt) * 512 + lane * 8];
    for (int mt = 0; mt < 4; ++mt)
      for (int nt = 0; nt < 4; ++nt)
        acc[mt][nt] = MFMA16(af[mt], bfr[nt], acc[mt][nt]);
  }

  const int b  = m0 >> 11;            // m0 / 2048
  const int l0 = m0 & (L_ - 1);
  const int h  = n0 / 384;
  const int which = (n0 % 384) >> 7;  // 0=q 1=k 2=v
  const int rlane = (lane >> 4) << 2; // C/D row base = (lane>>4)*4
  const int clane = lane & 15;        // C/D col = lane&15

  float bcol[4];
  for (int nt = 0; nt < 4; ++nt)
    bcol[nt] = bias[n0 + wn * 64 + nt * 16 + clane];

  if (which < 2) {
    // fused L2 normalize over this head's 128 columns (all inside this block)
    __syncthreads();                    // all waves done ds_reading As
    float* NormS = (float*)&As[0];      // [128 rows][2 wn-halves] fp32, 1KB, aliases As
    for (int mt = 0; mt < 4; ++mt)
      for (int r = 0; r < 4; ++r) {
        float sq = 0.f;
        for (int nt = 0; nt < 4; ++nt) {
          float v = acc[mt][nt][r] + bcol[nt];
          acc[mt][nt][r] = v;           // keep biased value for the write
          sq += v * v;
        }
        for (int off = 8; off; off >>= 1) sq += __shfl_xor(sq, off);  // 16-lane row group
        if (clane == 0) NormS[(wm * 64 + mt * 16 + rlane + r) * 2 + wn] = sq;
      }
    __syncthreads();
    float invn[4][4];
    for (int mt = 0; mt < 4; ++mt)
      for (int r = 0; r < 4; ++r) {
        int ll = wm * 64 + mt * 16 + rlane + r;
        float tot = NormS[ll * 2] + NormS[ll * 2 + 1];
        invn[mt][r] = 1.0f / fmaxf(sqrtf(tot), 1e-12f);   // matches F.normalize eps
      }
    bf16_t* base = ((which == 0) ? q : k) + ((size_t)(b * H_ + h) * L_) * HD_;
    for (int mt = 0; mt < 4; ++mt)
      for (int r = 0; r < 4; ++r) {
        int l = l0 + wm * 64 + mt * 16 + rlane + r;
        bf16_t* rowp = base + (size_t)l * HD_;
        for (int nt = 0; nt < 4; ++nt) {
          int hd = wn * 64 + nt * 16 + clane;
          rowp[hd] = (__bf16)(acc[mt][nt][r] * invn[mt][r]);
        }
      }
  } else {
    bf16_t* base = vT + ((size_t)(b * H_ + h) * HD_) * L_;
    for (int mt = 0; mt < 4; ++mt)
      for (int r = 0; r < 4; ++r) {
        int l = l0 + wm * 64 + mt * 16 + rlane + r;
        for (int nt = 0; nt < 4; ++nt) {
          int hd = wn * 64 + nt * 16 + clane;
          base[(size_t)hd * L_ + l] = (__bf16)(acc[mt][nt][r] + bcol[nt]);
        }
      }
  }
}

// ---------------------------------------------------------------------------
// Kernel 3: flash-style attention (verified in round 1; unchanged).
//   - cosine scores (|S|<=1) => softmax-lite: p=exp(s), denom reduced once.
//   - Q fragments in registers; private P buffer; 2 barriers/iter.
//   - T14 async staging; T5 setprio.
// LDS: Ks 16KB + Vts 16KB + Ps 16KB = 48KB. Output fp32 [B,L,H,HD].
// ---------------------------------------------------------------------------
__device__ __forceinline__ int swz128(int r, int c) {
  return r * 128 + ((((c >> 3) ^ (r & 15)) & 15) << 3) + (c & 7);
}
__device__ __forceinline__ int swz64(int r, int c) {
  return r * 64 + ((((c >> 3) ^ (r & 7)) & 7) << 3) + (c & 7);
}

__global__ __launch_bounds__(256) void attn(
    const bf16_t* __restrict__ q, const bf16_t* __restrict__ k,
    const bf16_t* __restrict__ vT, float* __restrict__ out)
{
  __shared__ alignas(16) bf16_t Ks[64 * 128];   // [j][d], swizzled
  __shared__ alignas(16) bf16_t Vts[128 * 64];  // [d][j], swizzled
  __shared__ alignas(16) bf16_t Ps[128 * 64];   // [l][j], swizzled (own-wave rows)

  const int tid = threadIdx.x, wave = tid >> 6, lane = tid & 63;
  const int bh = blockIdx.y;
  const int q0 = blockIdx.x * 128;
  const int rowf = lane & 15, kq8 = (lane >> 4) * 8;

  const bf16_t* qbase = q + ((size_t)bh * L_ + q0) * HD_;
  const bf16_t* kbh = k + (size_t)bh * L_ * HD_;
  const bf16_t* vbh = vT + (size_t)bh * HD_ * L_;

  // Q fragments: loop-invariant, straight from global (one-time, L2-served)
  bf16x8 qf[4][2];
  for (int kk4 = 0; kk4 < 4; ++kk4)
    for (int mt = 0; mt < 2; ++mt)
      qf[kk4][mt] = *(const bf16x8*)&qbase[(size_t)(wave * 32 + mt * 16 + rowf) * HD_ + kk4 * 32 + kq8];

  const f32x4 fzero = {0.f, 0.f, 0.f, 0.f};
  f32x4 o[2][8];
  for (int mt = 0; mt < 2; ++mt)
    for (int nt = 0; nt < 8; ++nt) o[mt][nt] = fzero;
  float lrow[2][4];
  for (int mt = 0; mt < 2; ++mt)
    for (int r = 0; r < 4; ++r) lrow[mt][r] = 0.f;

  // staging registers (async prefetch)
  bf16x8 kreg[4], vreg[4];

  // ---- prologue: tile 0 load + store ----
  for (int i = 0; i < 4; ++i) {
    int e = (i * 256 + tid) * 8;
    kreg[i] = *(const bf16x8*)&kbh[e];
  }
  for (int i = 0; i < 4; ++i) {
    int e = (i * 256 + tid) * 8;
    int d = e >> 6, c = e & 63;
    vreg[i] = *(const bf16x8*)&vbh[(size_t)d * L_ + c];
  }
  for (int i = 0; i < 4; ++i) {
    int e = (i * 256 + tid) * 8;
    *(bf16x8*)&Ks[swz128(e >> 7, e & 127)] = kreg[i];
  }
  for (int i = 0; i < 4; ++i) {
    int e = (i * 256 + tid) * 8;
    int d = e >> 6, c = e & 63;
    *(bf16x8*)&Vts[swz64(d, c)] = vreg[i];
  }
  __syncthreads();

  for (int j0 = 0; j0 < L_; j0 += 64) {
    const bool more = (j0 + 64 < L_);
    // issue next tile's loads now; latency hides under QK^T + softmax + PV
    if (more) {
      const int jn = j0 + 64;
      for (int i = 0; i < 4; ++i) {
        int e = (i * 256 + tid) * 8;
        kreg[i] = *(const bf16x8*)&kbh[(size_t)jn * HD_ + e];
      }
      for (int i = 0; i < 4; ++i) {
        int e = (i * 256 + tid) * 8;
        int d = e >> 6, c = e & 63;
        vreg[i] = *(const bf16x8*)&vbh[(size_t)d * L_ + jn + c];
      }
    }

    // S = Q K^T
    f32x4 s[2][4];
    for (int mt = 0; mt < 2; ++mt)
      for (int nt = 0; nt < 4; ++nt) s[mt][nt] = fzero;
    __builtin_amdgcn_s_setprio(1);
    for (int kk = 0; kk < 128; kk += 32) {
      bf16x8 bk4[4];
      for (int nt = 0; nt < 4; ++nt) bk4[nt] = *(const bf16x8*)&Ks[swz128(nt * 16 + rowf, kk + kq8)];
      for (int mt = 0; mt < 2; ++mt)
        for (int nt = 0; nt < 4; ++nt)
          s[mt][nt] = MFMA16(qf[kk >> 5][mt], bk4[nt], s[mt][nt]);
    }
    __builtin_amdgcn_s_setprio(0);

    // softmax-lite: |s| <= 1, so p = exp(s) is unconditionally stable.
    for (int mt = 0; mt < 2; ++mt)
      for (int nt = 0; nt < 4; ++nt)
        for (int r = 0; r < 4; ++r) {
          float p = __expf(s[mt][nt][r]);
          lrow[mt][r] += p;
          int rr = wave * 32 + mt * 16 + ((lane >> 4) << 2) + r;
          int cc = nt * 16 + (lane & 15);
          Ps[swz64(rr, cc)] = (__bf16)p;
        }

    // O += P @ V   (P rows are own-wave only: intra-wave lgkmcnt ordering)
    __builtin_amdgcn_s_setprio(1);
    for (int kk = 0; kk < 64; kk += 32) {
      bf16x8 ap[2];
      for (int mt = 0; mt < 2; ++mt)
        ap[mt] = *(const bf16x8*)&Ps[swz64(wave * 32 + mt * 16 + rowf, kk + kq8)];
      for (int nt = 0; nt < 8; ++nt) {
        bf16x8 bvv = *(const bf16x8*)&Vts[swz64(nt * 16 + rowf, kk + kq8)];
        for (int mt = 0; mt < 2; ++mt)
          o[mt][nt] = MFMA16(ap[mt], bvv, o[mt][nt]);
      }
    }
    __builtin_amdgcn_s_setprio(0);

    __syncthreads();          // all waves done reading Ks/Vts
    if (more) {
      for (int i = 0; i < 4; ++i) {
        int e = (i * 256 + tid) * 8;
        *(bf16x8*)&Ks[swz128(e >> 7, e & 127)] = kreg[i];
      }
      for (int i = 0; i < 4; ++i) {
        int e = (i * 256 + tid) * 8;
        int d = e >> 6, c = e & 63;
        *(bf16x8*)&Vts[swz64(d, c)] = vreg[i];
      }
      __syncthreads();
    }
  }

  // epilogue: single denom reduce, divide, write fp32 out [B][L][H][HD]
  const int b = bh >> 4, h = bh & 15;
  for (int mt = 0; mt < 2; ++mt) {
    for (int r = 0; r < 4; ++r) {
      float lsum = lrow[mt][r];
      for (int off = 8; off; off >>= 1) lsum += __shfl_xor(lsum, off);
      float inv = 1.0f / lsum;
      int l = q0 + wave * 32 + mt * 16 + ((lane >> 4) << 2) + r;
      float* op = out + (((size_t)b * L_ + l) * H_ + h) * HD_;
      for (int nt = 0; nt < 8; ++nt) {
        int d = nt * 16 + (lane & 15);
        op[d] = o[mt][nt][r] * inv;
      }
    }
  }
}

// ---------------------------------------------------------------------------
extern "C" void kernel_launch(void* const* d_in, const int* in_sizes, int n_in,
                              void* d_out, int out_size, void* d_ws, size_t ws_size,
                              hipStream_t stream)
{
  const float* X    = (const float*)d_in[0];   // [4,2048,2048] fp32
  const float* W    = (const float*)d_in[1];   // [6144,2048] fp32
  const float* bias = (const float*)d_in[2];   // [6144] fp32
  float* out = (float*)d_out;                  // [4,2048,2048] fp32

  // bf16 copies of X and W live inside d_out (58.7MB < 67.1MB); d_out is not
  // written by anything until attn, which runs after gemm_qkv has consumed them.
  bf16_t* Xb = (bf16_t*)d_out;
  bf16_t* Wb = Xb + NX;

  bf16_t* q  = (bf16_t*)d_ws;                  // [B,H,L,HD] 32MB (L2-normalized)
  bf16_t* k  = q + QK_ELEMS;                   // 32MB (L2-normalized)
  bf16_t* vT = k + QK_ELEMS;                   // [B,H,HD,L] 32MB

  cvt<<<dim3((NX + NW) / (256 * 4)), 256, 0, stream>>>(X, W, Xb);
  gemm_qkv<<<dim3(48, 64), 256, 0, stream>>>(Xb, Wb, bias, q, k, vT);
  attn<<<dim3(16, 64), 256, 0, stream>>>(q, k, vT, out);
}

// Round 5
// 634.561 us; speedup vs baseline: 1.2297x; 1.2291x over previous
//
#include <hip/hip_runtime.h>
#include <hip/hip_bf16.h>

typedef __bf16 bf16_t;
typedef __bf16 bf16x8 __attribute__((ext_vector_type(8)));
typedef __bf16 bf16x4 __attribute__((ext_vector_type(4)));
typedef __bf16 bf16x2 __attribute__((ext_vector_type(2)));
typedef float f32x4 __attribute__((ext_vector_type(4)));

#define MFMA16(a,b,c) __builtin_amdgcn_mfma_f32_16x16x32_bf16((a),(b),(c),0,0,0)
#define AS3(p) ((__attribute__((address_space(3))) void*)(p))
#define AS1(p) ((const __attribute__((address_space(1))) void*)(p))

constexpr int B_ = 4, L_ = 2048, E_ = 2048, H_ = 16, HD_ = 128;
constexpr size_t QK_ELEMS = (size_t)B_ * H_ * L_ * HD_;    // 16,777,216
constexpr size_t NX = (size_t)B_ * L_ * E_;                // 16,777,216
constexpr size_t NW = (size_t)3 * E_ * E_;                 // 12,582,912

// ---------------------------------------------------------------------------
// Kernel 0: fp32 -> bf16 conversion of X and W into one contiguous dst
// (dst lives in d_out's first 58.7MB; overwritten later by attn's output).
// ---------------------------------------------------------------------------
__global__ __launch_bounds__(256) void cvt(
    const float* __restrict__ X, const float* __restrict__ W, bf16_t* __restrict__ dst)
{
  size_t e = ((size_t)blockIdx.x * 256 + threadIdx.x) * 4;
  f32x4 v = (e < NX) ? *(const f32x4*)&X[e] : *(const f32x4*)&W[e - NX];
  bf16x4 o;
  for (int u = 0; u < 4; ++u) o[u] = (__bf16)v[u];
  *(bf16x4*)&dst[e] = o;
}

// ---------------------------------------------------------------------------
// Kernel 1: y = Xb @ Wb^T + b, fused with F.normalize for q/k.
// 128x128 tile, 4 waves 2x2. EXACT r2 staging (coalesced: lane = row lane>>2,
// chunk lane&3 -> 64B runs; r3/r4 proved the transposed source costs +130us)
// and EXACT r2 LDS layout/read ([row][32]; its 8-way conflicts are hidden on
// this 2-barrier structure per T2's regime gate — r2 measured 296us WITH
// 2.5e7 conflicts, r3/r4 measured 422-432us WITHOUT).
// NEW: 2 K-steps per barrier pair (BK=64 as two BK=32 buffers, 32KB LDS):
// halves the vmcnt(0)+s_barrier drains, nothing else changes.
// Epilogue fuses L2 normalization for q/k (r3/r4-proven correct) and
// scatters q,k -> [B,H,L,HD], v -> vT [B,H,HD,L] (bf16).
// ---------------------------------------------------------------------------
__global__ __launch_bounds__(256) void gemm_qkv(
    const bf16_t* __restrict__ Xb, const bf16_t* __restrict__ Wb, const float* __restrict__ bias,
    bf16_t* __restrict__ q, bf16_t* __restrict__ k, bf16_t* __restrict__ vT)
{
  __shared__ alignas(16) bf16_t As[2][128 * 32];   // [half][m][k], 64B rows, 16KB
  __shared__ alignas(16) bf16_t Bs[2][128 * 32];   // 16KB
  const int tid = threadIdx.x;
  const int wave = tid >> 6, lane = tid & 63;
  const int wm = wave >> 1, wn = wave & 1;
  const int m0 = blockIdx.y * 128, n0 = blockIdx.x * 128;
  const int rowf = lane & 15, kq8 = (lane >> 4) * 8;

  // staging (r2-exact): wave w owns rows [w*32, w*32+32), 2 insts x 16 rows.
  // lane i covers row (i>>2), 16B chunk (i&3) -- LDS dest = base + i*16B,
  // which lands exactly at As[h][row*32 + (i&3)*8] (contiguous [row][32]).
  const int srow = wave * 32 + (lane >> 2);
  const int scol = (lane & 3) * 8;
  const bf16_t* gA0 = &Xb[(size_t)(m0 + srow) * E_ + scol];
  const bf16_t* gB0 = &Wb[(size_t)(n0 + srow) * E_ + scol];
  bf16_t* lA0 = &As[0][(wave * 32) * 32];
  bf16_t* lA1 = &As[0][(wave * 32 + 16) * 32];
  bf16_t* lB0 = &Bs[0][(wave * 32) * 32];
  bf16_t* lB1 = &Bs[0][(wave * 32 + 16) * 32];
  constexpr int HBUF = 128 * 32;   // elems per half-buffer

  const f32x4 fzero = {0.f, 0.f, 0.f, 0.f};
  f32x4 acc[4][4];
  for (int i = 0; i < 4; ++i)
    for (int j = 0; j < 4; ++j) acc[i][j] = fzero;

  for (int k0 = 0; k0 < E_; k0 += 64) {
    __syncthreads();
    // half 0: K columns [k0, k0+32)
    __builtin_amdgcn_global_load_lds(AS1(gA0 + k0),                 AS3(lA0), 16, 0, 0);
    __builtin_amdgcn_global_load_lds(AS1(gA0 + 16 * E_ + k0),       AS3(lA1), 16, 0, 0);
    __builtin_amdgcn_global_load_lds(AS1(gB0 + k0),                 AS3(lB0), 16, 0, 0);
    __builtin_amdgcn_global_load_lds(AS1(gB0 + 16 * E_ + k0),       AS3(lB1), 16, 0, 0);
    // half 1: K columns [k0+32, k0+64)
    __builtin_amdgcn_global_load_lds(AS1(gA0 + k0 + 32),            AS3(lA0 + HBUF), 16, 0, 0);
    __builtin_amdgcn_global_load_lds(AS1(gA0 + 16 * E_ + k0 + 32),  AS3(lA1 + HBUF), 16, 0, 0);
    __builtin_amdgcn_global_load_lds(AS1(gB0 + k0 + 32),            AS3(lB0 + HBUF), 16, 0, 0);
    __builtin_amdgcn_global_load_lds(AS1(gB0 + 16 * E_ + k0 + 32),  AS3(lB1 + HBUF), 16, 0, 0);
    __syncthreads();
    for (int h = 0; h < 2; ++h) {
      bf16x8 af[4], bfr[4];
      for (int mt = 0; mt < 4; ++mt) af[mt]  = *(const bf16x8*)&As[h][(wm * 64 + mt * 16 + rowf) * 32 + kq8];
      for (int nt = 0; nt < 4; ++nt) bfr[nt] = *(const bf16x8*)&Bs[h][(wn * 64 + nt * 16 + rowf) * 32 + kq8];
      for (int mt = 0; mt < 4; ++mt)
        for (int nt = 0; nt < 4; ++nt)
          acc[mt][nt] = MFMA16(af[mt], bfr[nt], acc[mt][nt]);
    }
  }

  const int b  = m0 >> 11;            // m0 / 2048
  const int l0 = m0 & (L_ - 1);
  const int h  = n0 / 384;
  const int which = (n0 % 384) >> 7;  // 0=q 1=k 2=v
  const int rlane = (lane >> 4) << 2; // C/D row base = (lane>>4)*4
  const int clane = lane & 15;        // C/D col = lane&15

  float bcol[4];
  for (int nt = 0; nt < 4; ++nt)
    bcol[nt] = bias[n0 + wn * 64 + nt * 16 + clane];

  if (which < 2) {
    // fused L2 normalize over this head's 128 columns (all inside this block)
    __syncthreads();                    // all waves done ds_reading As
    float* NormS = (float*)&As[0][0];   // [128 rows][2 wn-halves] fp32, 1KB
    for (int mt = 0; mt < 4; ++mt)
      for (int r = 0; r < 4; ++r) {
        float sq = 0.f;
        for (int nt = 0; nt < 4; ++nt) {
          float v = acc[mt][nt][r] + bcol[nt];
          acc[mt][nt][r] = v;           // keep biased value for the write
          sq += v * v;
        }
        for (int off = 8; off; off >>= 1) sq += __shfl_xor(sq, off);  // 16-lane row group
        if (clane == 0) NormS[(wm * 64 + mt * 16 + rlane + r) * 2 + wn] = sq;
      }
    __syncthreads();
    float invn[4][4];
    for (int mt = 0; mt < 4; ++mt)
      for (int r = 0; r < 4; ++r) {
        int ll = wm * 64 + mt * 16 + rlane + r;
        float tot = NormS[ll * 2] + NormS[ll * 2 + 1];
        invn[mt][r] = 1.0f / fmaxf(sqrtf(tot), 1e-12f);   // matches F.normalize eps
      }
    bf16_t* base = ((which == 0) ? q : k) + ((size_t)(b * H_ + h) * L_) * HD_;
    for (int mt = 0; mt < 4; ++mt)
      for (int r = 0; r < 4; ++r) {
        int l = l0 + wm * 64 + mt * 16 + rlane + r;
        bf16_t* rowp = base + (size_t)l * HD_;
        for (int nt = 0; nt < 4; ++nt) {
          int hd = wn * 64 + nt * 16 + clane;
          rowp[hd] = (__bf16)(acc[mt][nt][r] * invn[mt][r]);
        }
      }
  } else {
    bf16_t* base = vT + ((size_t)(b * H_ + h) * HD_) * L_;
    for (int mt = 0; mt < 4; ++mt)
      for (int r = 0; r < 4; ++r) {
        int l = l0 + wm * 64 + mt * 16 + rlane + r;
        for (int nt = 0; nt < 4; ++nt) {
          int hd = wn * 64 + nt * 16 + clane;
          base[(size_t)hd * L_ + l] = (__bf16)(acc[mt][nt][r] + bcol[nt]);
        }
      }
  }
}

// ---------------------------------------------------------------------------
// Kernel 3: flash-style attention (verified in round 1; unchanged).
//   - cosine scores (|S|<=1) => softmax-lite: p=exp(s), denom reduced once.
//   - Q fragments in registers; private P buffer; 2 barriers/iter.
//   - T14 async staging; T5 setprio.
// LDS: Ks 16KB + Vts 16KB + Ps 16KB = 48KB. Output fp32 [B,L,H,HD].
// ---------------------------------------------------------------------------
__device__ __forceinline__ int swz128(int r, int c) {
  return r * 128 + ((((c >> 3) ^ (r & 15)) & 15) << 3) + (c & 7);
}
__device__ __forceinline__ int swz64(int r, int c) {
  return r * 64 + ((((c >> 3) ^ (r & 7)) & 7) << 3) + (c & 7);
}

__global__ __launch_bounds__(256) void attn(
    const bf16_t* __restrict__ q, const bf16_t* __restrict__ k,
    const bf16_t* __restrict__ vT, float* __restrict__ out)
{
  __shared__ alignas(16) bf16_t Ks[64 * 128];   // [j][d], swizzled
  __shared__ alignas(16) bf16_t Vts[128 * 64];  // [d][j], swizzled
  __shared__ alignas(16) bf16_t Ps[128 * 64];   // [l][j], swizzled (own-wave rows)

  const int tid = threadIdx.x, wave = tid >> 6, lane = tid & 63;
  const int bh = blockIdx.y;
  const int q0 = blockIdx.x * 128;
  const int rowf = lane & 15, kq8 = (lane >> 4) * 8;

  const bf16_t* qbase = q + ((size_t)bh * L_ + q0) * HD_;
  const bf16_t* kbh = k + (size_t)bh * L_ * HD_;
  const bf16_t* vbh = vT + (size_t)bh * HD_ * L_;

  // Q fragments: loop-invariant, straight from global (one-time, L2-served)
  bf16x8 qf[4][2];
  for (int kk4 = 0; kk4 < 4; ++kk4)
    for (int mt = 0; mt < 2; ++mt)
      qf[kk4][mt] = *(const bf16x8*)&qbase[(size_t)(wave * 32 + mt * 16 + rowf) * HD_ + kk4 * 32 + kq8];

  const f32x4 fzero = {0.f, 0.f, 0.f, 0.f};
  f32x4 o[2][8];
  for (int mt = 0; mt < 2; ++mt)
    for (int nt = 0; nt < 8; ++nt) o[mt][nt] = fzero;
  float lrow[2][4];
  for (int mt = 0; mt < 2; ++mt)
    for (int r = 0; r < 4; ++r) lrow[mt][r] = 0.f;

  // staging registers (async prefetch)
  bf16x8 kreg[4], vreg[4];

  // ---- prologue: tile 0 load + store ----
  for (int i = 0; i < 4; ++i) {
    int e = (i * 256 + tid) * 8;
    kreg[i] = *(const bf16x8*)&kbh[e];
  }
  for (int i = 0; i < 4; ++i) {
    int e = (i * 256 + tid) * 8;
    int d = e >> 6, c = e & 63;
    vreg[i] = *(const bf16x8*)&vbh[(size_t)d * L_ + c];
  }
  for (int i = 0; i < 4; ++i) {
    int e = (i * 256 + tid) * 8;
    *(bf16x8*)&Ks[swz128(e >> 7, e & 127)] = kreg[i];
  }
  for (int i = 0; i < 4; ++i) {
    int e = (i * 256 + tid) * 8;
    int d = e >> 6, c = e & 63;
    *(bf16x8*)&Vts[swz64(d, c)] = vreg[i];
  }
  __syncthreads();

  for (int j0 = 0; j0 < L_; j0 += 64) {
    const bool more = (j0 + 64 < L_);
    // issue next tile's loads now; latency hides under QK^T + softmax + PV
    if (more) {
      const int jn = j0 + 64;
      for (int i = 0; i < 4; ++i) {
        int e = (i * 256 + tid) * 8;
        kreg[i] = *(const bf16x8*)&kbh[(size_t)jn * HD_ + e];
      }
      for (int i = 0; i < 4; ++i) {
        int e = (i * 256 + tid) * 8;
        int d = e >> 6, c = e & 63;
        vreg[i] = *(const bf16x8*)&vbh[(size_t)d * L_ + jn + c];
      }
    }

    // S = Q K^T
    f32x4 s[2][4];
    for (int mt = 0; mt < 2; ++mt)
      for (int nt = 0; nt < 4; ++nt) s[mt][nt] = fzero;
    __builtin_amdgcn_s_setprio(1);
    for (int kk = 0; kk < 128; kk += 32) {
      bf16x8 bk4[4];
      for (int nt = 0; nt < 4; ++nt) bk4[nt] = *(const bf16x8*)&Ks[swz128(nt * 16 + rowf, kk + kq8)];
      for (int mt = 0; mt < 2; ++mt)
        for (int nt = 0; nt < 4; ++nt)
          s[mt][nt] = MFMA16(qf[kk >> 5][mt], bk4[nt], s[mt][nt]);
    }
    __builtin_amdgcn_s_setprio(0);

    // softmax-lite: |s| <= 1, so p = exp(s) is unconditionally stable.
    for (int mt = 0; mt < 2; ++mt)
      for (int nt = 0; nt < 4; ++nt)
        for (int r = 0; r < 4; ++r) {
          float p = __expf(s[mt][nt][r]);
          lrow[mt][r] += p;
          int rr = wave * 32 + mt * 16 + ((lane >> 4) << 2) + r;
          int cc = nt * 16 + (lane & 15);
          Ps[swz64(rr, cc)] = (__bf16)p;
        }

    // O += P @ V   (P rows are own-wave only: intra-wave lgkmcnt ordering)
    __builtin_amdgcn_s_setprio(1);
    for (int kk = 0; kk < 64; kk += 32) {
      bf16x8 ap[2];
      for (int mt = 0; mt < 2; ++mt)
        ap[mt] = *(const bf16x8*)&Ps[swz64(wave * 32 + mt * 16 + rowf, kk + kq8)];
      for (int nt = 0; nt < 8; ++nt) {
        bf16x8 bvv = *(const bf16x8*)&Vts[swz64(nt * 16 + rowf, kk + kq8)];
        for (int mt = 0; mt < 2; ++mt)
          o[mt][nt] = MFMA16(ap[mt], bvv, o[mt][nt]);
      }
    }
    __builtin_amdgcn_s_setprio(0);

    __syncthreads();          // all waves done reading Ks/Vts
    if (more) {
      for (int i = 0; i < 4; ++i) {
        int e = (i * 256 + tid) * 8;
        *(bf16x8*)&Ks[swz128(e >> 7, e & 127)] = kreg[i];
      }
      for (int i = 0; i < 4; ++i) {
        int e = (i * 256 + tid) * 8;
        int d = e >> 6, c = e & 63;
        *(bf16x8*)&Vts[swz64(d, c)] = vreg[i];
      }
      __syncthreads();
    }
  }

  // epilogue: single denom reduce, divide, write fp32 out [B][L][H][HD]
  const int b = bh >> 4, h = bh & 15;
  for (int mt = 0; mt < 2; ++mt) {
    for (int r = 0; r < 4; ++r) {
      float lsum = lrow[mt][r];
      for (int off = 8; off; off >>= 1) lsum += __shfl_xor(lsum, off);
      float inv = 1.0f / lsum;
      int l = q0 + wave * 32 + mt * 16 + ((lane >> 4) << 2) + r;
      float* op = out + (((size_t)b * L_ + l) * H_ + h) * HD_;
      for (int nt = 0; nt < 8; ++nt) {
        int d = nt * 16 + (lane & 15);
        op[d] = o[mt][nt][r] * inv;
      }
    }
  }
}

// ---------------------------------------------------------------------------
extern "C" void kernel_launch(void* const* d_in, const int* in_sizes, int n_in,
                              void* d_out, int out_size, void* d_ws, size_t ws_size,
                              hipStream_t stream)
{
  const float* X    = (const float*)d_in[0];   // [4,2048,2048] fp32
  const float* W    = (const float*)d_in[1];   // [6144,2048] fp32
  const float* bias = (const float*)d_in[2];   // [6144] fp32
  float* out = (float*)d_out;                  // [4,2048,2048] fp32

  // bf16 copies of X and W live inside d_out (58.7MB < 67.1MB); d_out is not
  // written by anything until attn, which runs after gemm_qkv has consumed them.
  bf16_t* Xb = (bf16_t*)d_out;
  bf16_t* Wb = Xb + NX;

  bf16_t* q  = (bf16_t*)d_ws;                  // [B,H,L,HD] 32MB (L2-normalized)
  bf16_t* k  = q + QK_ELEMS;                   // 32MB (L2-normalized)
  bf16_t* vT = k + QK_ELEMS;                   // [B,H,HD,L] 32MB

  cvt<<<dim3((NX + NW) / (256 * 4)), 256, 0, stream>>>(X, W, Xb);
  gemm_qkv<<<dim3(48, 64), 256, 0, stream>>>(Xb, Wb, bias, q, k, vT);
  attn<<<dim3(16, 64), 256, 0, stream>>>(q, k, vT, out);
}